// Round 9
// baseline (308.877 us; speedup 1.0000x reference)
//
#include <hip/hip_runtime.h>

typedef unsigned short u16;
typedef __attribute__((ext_vector_type(8))) __bf16 bf16x8;
typedef __attribute__((ext_vector_type(4))) float f32x4;
typedef __attribute__((ext_vector_type(4))) u16 u16x4;
typedef __attribute__((ext_vector_type(8))) u16 u16x8;

constexpr int S = 2048;
constexpr int H = 2048;
constexpr int NH = 16;
constexpr int HD = 128;
constexpr int M = 4096;   // B*S
constexpr float SCALE = 0.08838834764831845f;  // 1/sqrt(128)

__device__ __forceinline__ u16 f2bf(float f) {
  union { float f; unsigned u; } v; v.f = f;
  unsigned r = v.u + 0x7fffu + ((v.u >> 16) & 1u);  // RNE
  return (u16)(r >> 16);
}
__device__ __forceinline__ float bf2f(u16 u) {
  union { unsigned u; float f; } v; v.u = ((unsigned)u) << 16;
  return v.f;
}
__device__ __forceinline__ unsigned cvt_pk_bf16(float lo, float hi) {
  unsigned r;
  asm("v_cvt_pk_bf16_f32 %0, %1, %2" : "=v"(r) : "v"(lo), "v"(hi));
  return r;
}
__device__ __forceinline__ f32x4 MFMA16(bf16x8 a, bf16x8 b, f32x4 c) {
  return __builtin_amdgcn_mfma_f32_16x16x32_bf16(a, b, c, 0, 0, 0);
}

// async global->LDS, 16 bytes per lane. LDS dest must be wave-uniform base + lane*16.
__device__ __forceinline__ void gld16(const u16* g, u16* l) {
  __builtin_amdgcn_global_load_lds(
      (const __attribute__((address_space(1))) void*)g,
      (__attribute__((address_space(3))) void*)l, 16, 0, 0);
}

#define BAR  __builtin_amdgcn_s_barrier()

// ---------------- fp32 -> bf16 cast (x) ----------------
__global__ __launch_bounds__(256) void cast_kernel(const float* __restrict__ in,
                                                   u16* __restrict__ out, int n) {
  int i = (blockIdx.x * 256 + threadIdx.x) * 4;
  if (i >= n) return;
  float4 v = *(const float4*)(in + i);
  u16x4 o;
  o[0] = f2bf(v.x); o[1] = f2bf(v.y); o[2] = f2bf(v.z); o[3] = f2bf(v.w);
  *(u16x4*)(out + i) = o;
}

// ---------------- 4 weight casts in one dispatch ----------------
__global__ __launch_bounds__(256) void cast4_kernel(const float* __restrict__ i0,
                                                    const float* __restrict__ i1,
                                                    const float* __restrict__ i2,
                                                    const float* __restrict__ i3,
                                                    u16* o0, u16* o1, u16* o2, u16* o3) {
  const float* in; u16* out;
  switch (blockIdx.y) {
    case 0: in = i0; out = o0; break;
    case 1: in = i1; out = o1; break;
    case 2: in = i2; out = o2; break;
    default: in = i3; out = o3; break;
  }
  int i = (blockIdx.x * 256 + threadIdx.x) * 4;
  float4 v = *(const float4*)(in + i);
  u16x4 o;
  o[0] = f2bf(v.x); o[1] = f2bf(v.y); o[2] = f2bf(v.z); o[3] = f2bf(v.w);
  *(u16x4*)(out + i) = o;
}

// ---------------- concat biases into [6144] ----------------
__global__ __launch_bounds__(256) void concat_bias_k(const float* __restrict__ bq,
                                                     const float* __restrict__ bk,
                                                     const float* __restrict__ bv,
                                                     float* __restrict__ bqkv) {
  int i = blockIdx.x * 256 + threadIdx.x;  // 0..6143
  const float* src = (i < 2048) ? bq : (i < 4096) ? bk : bv;
  bqkv[i] = src[i & 2047];
}

// ---------------- RoPE cos/sin table ----------------
__global__ __launch_bounds__(256) void rope_table_k(float* __restrict__ tab) {
  int i = blockIdx.x * 256 + threadIdx.x;
  if (i >= S * 64) return;
  int s = i >> 6, d = i & 63;
  float freq = expf(-(float)d * (9.210340371976184f / 64.f));  // 10000^(-d/64)
  float ang = (float)s * freq;
  tab[i * 2]     = cosf(ang);
  tab[i * 2 + 1] = sinf(ang);
}

// ================= fused QKV GEMM: 256x256 tile, 8 waves, T3-minimum 2-phase =================
// A[4096][2048] x Wqkv[6144][2048]^T. Grid 384 = 16(M) x 24(N), XCD-striped, 1 block/CU.
// 8 waves (2M x 4N), per-wave 128x64 out -> 24 b128-reads / 64 MFMA per K-tile (0.375/MFMA,
// vs 0.5 at 64x64 waves: LDS-throughput intensity +33%). ONE barrier per K-tile:
//   STAGE(next) -> {LDB/LDA4/MM16 x2 kh, compiler-scheduled} -> vmcnt(0) -> BAR.
// 2 waves/SIMD provide the stall hiding (same TLP as 2x 4-wave blocks).
// Chunk-XOR swizzle (source-swizzled stage, same involution on read) -> conflict-free.
// Epilogue: Q/K -> bias + RoPE (pair-exchange d^64 via wave w^1 through LDS); V -> bias+transpose.
__global__ __launch_bounds__(512, 2) void gemm_qkv256(const u16* __restrict__ A,
                                                      const u16* __restrict__ Bw,
                                                      const float* __restrict__ bias,
                                                      const float* __restrict__ tab,
                                                      u16* __restrict__ Qb,
                                                      u16* __restrict__ Kb,
                                                      u16* __restrict__ Vt) {
  __shared__ u16 AsL[2 * 256 * 64];   // 64 KiB
  __shared__ u16 BsL[2 * 256 * 64];   // 64 KiB

  const int id = blockIdx.x;
  const int xcd = id & 7, sid = id >> 3;        // sid 0..47
  const int bx = xcd * 3 + (sid % 3);           // 0..23 (per-XCD B-stripe 3 MB -> L2)
  const int by = sid / 3;                       // 0..15
  const int brow = by * 256, bcol = bx * 256;
  const int sel = bcol >> 11;                   // 0=Q 1=K 2=V (256-tile never crosses)

  const int t = threadIdx.x;                    // 0..511
  const int w = t >> 6, l = t & 63;
  const int wr = w >> 2, wc = w & 3;
  const int lr = l & 15, lg = l >> 4;
  const int swz = lr & 7;

  f32x4 acc[8][4] = {};

  const int sr = t >> 3, sj = t & 7;            // stage: 64 rows x 8 chunks per gld16 inst

  auto STAGE = [&](int BUF, int TILE) {
    u16* da = AsL + BUF * (256 * 64);
    const u16* sa = A + (size_t)brow * H + TILE * 64;
    #pragma unroll
    for (int it = 0; it < 4; ++it) {
      int row = it * 64 + sr;
      gld16(sa + (size_t)row * H + ((sj ^ (row & 7)) * 8), da + (it * 512 + t) * 8);
    }
    u16* db = BsL + BUF * (256 * 64);
    const u16* sb = Bw + (size_t)bcol * H + TILE * 64;
    #pragma unroll
    for (int it = 0; it < 4; ++it) {
      int row = it * 64 + sr;
      gld16(sb + (size_t)row * H + ((sj ^ (row & 7)) * 8), db + (it * 512 + t) * 8);
    }
  };
  auto LDB = [&](int BUF, int KH, bf16x8* bb) {
    const u16* base = BsL + BUF * (256 * 64) + (wc * 64 + lr) * 64;
    #pragma unroll
    for (int n = 0; n < 4; ++n)
      bb[n] = *(const bf16x8*)(base + n * (16 * 64) + (((KH * 4 + lg) ^ swz) * 8));
  };
  auto LDA4 = [&](int BUF, int KH, int MB, bf16x8* aa) {
    const u16* base = AsL + BUF * (256 * 64) + (wr * 128 + MB * 16 + lr) * 64;
    #pragma unroll
    for (int i = 0; i < 4; ++i)
      aa[i] = *(const bf16x8*)(base + i * (16 * 64) + (((KH * 4 + lg) ^ swz) * 8));
  };
  auto MM16 = [&](int MB, bf16x8* aa, bf16x8* bb) {
    __builtin_amdgcn_s_setprio(1);
    #pragma unroll
    for (int i = 0; i < 4; ++i)
      #pragma unroll
      for (int n = 0; n < 4; ++n)
        acc[MB + i][n] = MFMA16(aa[i], bb[n], acc[MB + i][n]);
    __builtin_amdgcn_s_setprio(0);
  };

  // prologue
  STAGE(0, 0);
  asm volatile("s_waitcnt vmcnt(0)" ::: "memory");
  BAR;

  int c = 0;
  for (int u = 0; u < 32; ++u) {
    if (u < 31) STAGE(c ^ 1, u + 1);   // issue next-tile loads FIRST
    bf16x8 aa[4], bb[4];
    LDB(c, 0, bb);
    LDA4(c, 0, 0, aa); MM16(0, aa, bb);
    LDA4(c, 0, 4, aa); MM16(4, aa, bb);
    LDB(c, 1, bb);
    LDA4(c, 1, 0, aa); MM16(0, aa, bb);
    LDA4(c, 1, 4, aa); MM16(4, aa, bb);
    asm volatile("s_waitcnt vmcnt(0)" ::: "memory");
    BAR;                                // next tile in LDS; this buffer free
    c ^= 1;
  }

  // ================= epilogue =================
  if (sel < 2) {
    // Q/K: bias + RoPE + bf16. Pair-exchange (d ^ 64 <-> wave w^1) via LDS.
    float* lf = (float*)AsL;            // 8 waves * 16*66 * 4B = 33.8 KiB
    u16* Cq = sel ? Kb : Qb;
    const float scl = sel ? 1.f : SCALE;
    #pragma unroll
    for (int m = 0; m < 8; ++m) {
      __syncthreads();                  // prev chunk / main-loop LDS reads done
      float mine[4][4];
      #pragma unroll
      for (int n = 0; n < 4; ++n) {
        const float bv = bias[bcol + wc * 64 + n * 16 + lr];
        #pragma unroll
        for (int r = 0; r < 4; ++r) {
          mine[n][r] = acc[m][n][r] + bv;
          lf[w * (16 * 66) + (lg * 4 + r) * 66 + n * 16 + lr] = mine[n][r];
        }
      }
      __syncthreads();
      #pragma unroll
      for (int n = 0; n < 4; ++n) {
        const int j = n * 16 + lr;                 // d & 63
        const int hcol = (bcol & 2047) + wc * 64 + j;
        #pragma unroll
        for (int r = 0; r < 4; ++r) {
          const int row = brow + wr * 128 + m * 16 + lg * 4 + r;
          const int s = row & (S - 1);
          float pr = lf[(w ^ 1) * (16 * 66) + (lg * 4 + r) * 66 + j];
          float2 cs = ((const float2*)tab)[s * 64 + j];
          float out = (wc & 1) ? (mine[n][r] * cs.x + pr * cs.y)
                               : (mine[n][r] * cs.x - pr * cs.y);
          Cq[(size_t)row * H + hcol] = f2bf(out * scl);
        }
      }
    }
  } else {
    // V: bias + transposed store Vt[((b*16+h)*128+d)*S + s]
    #pragma unroll
    for (int m = 0; m < 8; ++m) {
      const int row0 = brow + wr * 128 + m * 16 + lg * 4;
      #pragma unroll
      for (int n = 0; n < 4; ++n) {
        const int col = (bcol & 2047) + wc * 64 + n * 16 + lr;
        const float bv = bias[bcol + wc * 64 + n * 16 + lr];
        const int hh = col >> 7, d = col & 127;
        const int b = row0 >> 11, s0 = row0 & (S - 1);
        u16x4 pk;
        #pragma unroll
        for (int r = 0; r < 4; ++r) pk[r] = f2bf(acc[m][n][r] + bv);
        *(u16x4*)(Vt + ((size_t)((b * 16 + hh) * 128 + d)) * S + s0) = pk;
      }
    }
  }
}

// ================= out-proj: 128x128, BK=64, 256 thr, 2 blocks/CU (R8-proven) =================
__global__ __launch_bounds__(256, 2) void gemm_o2(const u16* __restrict__ A,
                                                  const u16* __restrict__ Bw,
                                                  const float* __restrict__ bias,
                                                  float* __restrict__ C) {
  __shared__ u16 AsL[2 * 128 * 64];   // 32 KiB
  __shared__ u16 BsL[2 * 128 * 64];   // 32 KiB
  const int id = blockIdx.x;
  const int xcd = id & 7, sid = id >> 3;        // sid 0..63
  const int bx = xcd * 2 + (sid & 1);           // 0..15
  const int by = sid >> 1;                      // 0..31
  const int brow = by * 128, bcol = bx * 128;

  const int t = threadIdx.x;
  const int w = t >> 6, l = t & 63;
  const int wr = w >> 1, wc = w & 1;
  const int lr = l & 15, lg = l >> 4;
  const int swz = lr & 7;

  f32x4 acc[4][4] = {};
  const int sr = t >> 3, sj = t & 7;

  auto STAGE = [&](int BUF, int TILE) {
    u16* da = AsL + BUF * (128 * 64);
    const u16* sa = A + (size_t)brow * H + TILE * 64;
    #pragma unroll
    for (int it = 0; it < 4; ++it) {
      int row = it * 32 + sr;
      gld16(sa + (size_t)row * H + ((sj ^ (row & 7)) * 8), da + (it * 256 + t) * 8);
    }
    u16* db = BsL + BUF * (128 * 64);
    const u16* sb = Bw + (size_t)bcol * H + TILE * 64;
    #pragma unroll
    for (int it = 0; it < 4; ++it) {
      int row = it * 32 + sr;
      gld16(sb + (size_t)row * H + ((sj ^ (row & 7)) * 8), db + (it * 256 + t) * 8);
    }
  };
  auto LDA = [&](int BUF, int KH, bf16x8* aa) {
    const u16* base = AsL + BUF * (128 * 64) + (wr * 64 + lr) * 64;
    #pragma unroll
    for (int i = 0; i < 4; ++i)
      aa[i] = *(const bf16x8*)(base + i * (16 * 64) + (((KH * 4 + lg) ^ swz) * 8));
  };
  auto LDB = [&](int BUF, int KH, bf16x8* bb) {
    const u16* base = BsL + BUF * (128 * 64) + (wc * 64 + lr) * 64;
    #pragma unroll
    for (int n = 0; n < 4; ++n)
      bb[n] = *(const bf16x8*)(base + n * (16 * 64) + (((KH * 4 + lg) ^ swz) * 8));
  };
  auto MM = [&](bf16x8* aa, bf16x8* bb) {
    __builtin_amdgcn_s_setprio(1);
    #pragma unroll
    for (int i = 0; i < 4; ++i)
      #pragma unroll
      for (int n = 0; n < 4; ++n)
        acc[i][n] = MFMA16(aa[i], bb[n], acc[i][n]);
    __builtin_amdgcn_s_setprio(0);
  };

  STAGE(0, 0);
  asm volatile("s_waitcnt vmcnt(0)" ::: "memory");
  BAR;

  int c = 0;
  for (int u = 0; u < 32; ++u) {
    if (u < 31) STAGE(c ^ 1, u + 1);
    bf16x8 aa[4], bb[4];
    LDA(c, 0, aa); LDB(c, 0, bb); MM(aa, bb);
    LDA(c, 1, aa); LDB(c, 1, bb); MM(aa, bb);
    asm volatile("s_waitcnt vmcnt(0)" ::: "memory");
    BAR;
    c ^= 1;
  }

  #pragma unroll
  for (int m = 0; m < 4; ++m) {
    const int row0 = brow + wr * 64 + m * 16 + lg * 4;
    #pragma unroll
    for (int n = 0; n < 4; ++n) {
      const int col = bcol + wc * 64 + n * 16 + lr;
      const float bv = bias[col];
      #pragma unroll
      for (int r = 0; r < 4; ++r)
        C[(size_t)(row0 + r) * H + col] = acc[m][n][r] + bv;
    }
  }
}

// ---------------- causal flash attention (unchanged) ----------------
__global__ __launch_bounds__(256) void attn_fwd(const u16* __restrict__ Q,
                                                const u16* __restrict__ Kx,
                                                const u16* __restrict__ Vt,
                                                u16* __restrict__ O) {
  const int id = blockIdx.x;
  const int xcd = id & 7, slot = id >> 3;
  const int bh = (slot >> 4) * 8 + xcd;    // 0..31
  const int pid = slot & 15;               // 0..15
  const int b = bh >> 4, h = bh & 15;
  const int t = threadIdx.x, w = t >> 6, l = t & 63;
  const int lr = l & 15, lg = l >> 4;
  const int swz = lr & 7;

  __shared__ u16 Ks[2][64 * 128];
  __shared__ u16 Vs[2][128 * 64];
  __shared__ u16 P_lds[4][16 * 64];
  u16* pw = &P_lds[w][0];

  const u16* kbase = Kx + (size_t)(b * S) * H + h * HD;
  const u16* vbase = Vt + (size_t)bh * HD * S;

  auto stageK = [&](int bf, int k0) {
    #pragma unroll
    for (int it = 0; it < 4; ++it) {
      int c = it * 256 + t;
      int row = c >> 4, j = c & 15;
      gld16(kbase + (size_t)(k0 + row) * H + ((j ^ (row & 7)) * 8), &Ks[bf][0] + c * 8);
    }
  };
  auto stageV = [&](int bf, int k0) {
    #pragma unroll
    for (int it = 0; it < 4; ++it) {
      int c = it * 256 + t;
      int row = c >> 3, j = c & 7;
      gld16(vbase + (size_t)row * S + k0 + ((j ^ (row & 7)) * 8), &Vs[bf][0] + c * 8);
    }
  };

  int cur = 0;
  for (int qi = 0; qi < 2; ++qi) {
    const int qt = qi ? pid : (31 - pid);
    const int q0 = qt * 64 + w * 16;

    bf16x8 qa[4];
    const u16* qbase = Q + (size_t)(b * S + q0 + lr) * H + h * HD;
    #pragma unroll
    for (int ks = 0; ks < 4; ++ks)
      qa[ks] = *(const bf16x8*)(qbase + ks * 32 + lg * 8);

    f32x4 acc[8] = {};
    float mrun[4], lrun[4];
    #pragma unroll
    for (int r = 0; r < 4; ++r) { mrun[r] = -1e30f; lrun[r] = 0.f; }

    __syncthreads();
    stageK(cur, 0);
    stageV(cur, 0);
    __syncthreads();

    for (int kt = 0; kt <= qt; ++kt) {
      if (kt < qt) {
        stageK(cur ^ 1, (kt + 1) * 64);
        stageV(cur ^ 1, (kt + 1) * 64);
      }
      const u16* kl = &Ks[cur][0];
      const u16* vl = &Vs[cur][0];

      f32x4 sc[4] = {};
      __builtin_amdgcn_s_setprio(1);
      #pragma unroll
      for (int ks = 0; ks < 4; ++ks) {
        #pragma unroll
        for (int f = 0; f < 4; ++f) {
          bf16x8 kf = *(const bf16x8*)(kl + (f * 16 + lr) * 128 + (((ks * 4 + lg) ^ swz) * 8));
          sc[f] = __builtin_amdgcn_mfma_f32_16x16x32_bf16(qa[ks], kf, sc[f], 0, 0, 0);
        }
      }
      __builtin_amdgcn_s_setprio(0);
      const bool diag = (kt == qt);
      float p[4][4];
      #pragma unroll
      for (int f = 0; f < 4; ++f)
        #pragma unroll
        for (int r = 0; r < 4; ++r) {
          float v = sc[f][r];
          if (diag && (f * 16 + lr > w * 16 + lg * 4 + r)) v = -1e30f;
          p[f][r] = v;
        }
      float mx[4];
      #pragma unroll
      for (int r = 0; r < 4; ++r) {
        float m0 = fmaxf(fmaxf(p[0][r], p[1][r]), fmaxf(p[2][r], p[3][r]));
        m0 = fmaxf(m0, __shfl_xor(m0, 1));
        m0 = fmaxf(m0, __shfl_xor(m0, 2));
        m0 = fmaxf(m0, __shfl_xor(m0, 4));
        m0 = fmaxf(m0, __shfl_xor(m0, 8));
        mx[r] = m0;
      }
      bool grow = (mx[0] > mrun[0] + 8.f) || (mx[1] > mrun[1] + 8.f) ||
                  (mx[2] > mrun[2] + 8.f) || (mx[3] > mrun[3] + 8.f);
      if (__any(grow)) {
        float resc[4];
        #pragma unroll
        for (int r = 0; r < 4; ++r) {
          float mnew = fmaxf(mrun[r], mx[r]);
          resc[r] = __expf(mrun[r] - mnew);
          mrun[r] = mnew;
          lrun[r] *= resc[r];
        }
        #pragma unroll
        for (int fd = 0; fd < 8; ++fd) {
          f32x4 a = acc[fd];
          a[0] *= resc[0]; a[1] *= resc[1]; a[2] *= resc[2]; a[3] *= resc[3];
          acc[fd] = a;
        }
      }
      #pragma unroll
      for (int r = 0; r < 4; ++r) {
        float sum = 0.f;
        #pragma unroll
        for (int f = 0; f < 4; ++f) {
          float e = __expf(p[f][r] - mrun[r]);
          p[f][r] = e;
          sum += e;
        }
        sum += __shfl_xor(sum, 1);
        sum += __shfl_xor(sum, 2);
        sum += __shfl_xor(sum, 4);
        sum += __shfl_xor(sum, 8);
        lrun[r] += sum;
      }
      {
        const int r0 = lg * 4;
        #pragma unroll
        for (int f = 0; f < 4; ++f) {
          const int col = f * 16 + lr;
          unsigned w01 = cvt_pk_bf16(p[f][0], p[f][1]);
          unsigned w23 = cvt_pk_bf16(p[f][2], p[f][3]);
          pw[(r0 + 0) * 64 + (col ^ (((r0 + 0) & 7) << 3))] = (u16)(w01 & 0xffffu);
          pw[(r0 + 1) * 64 + (col ^ (((r0 + 1) & 7) << 3))] = (u16)(w01 >> 16);
          pw[(r0 + 2) * 64 + (col ^ (((r0 + 2) & 7) << 3))] = (u16)(w23 & 0xffffu);
          pw[(r0 + 3) * 64 + (col ^ (((r0 + 3) & 7) << 3))] = (u16)(w23 >> 16);
        }
      }
      __builtin_amdgcn_s_setprio(1);
      #pragma unroll
      for (int ks = 0; ks < 2; ++ks) {
        int col0 = ks * 32 + lg * 8;
        bf16x8 pa = *(const bf16x8*)(pw + lr * 64 + (col0 ^ (swz << 3)));
        #pragma unroll
        for (int fd = 0; fd < 8; ++fd) {
          bf16x8 vb = *(const bf16x8*)(vl + (fd * 16 + lr) * 64 + (((ks * 4 + lg) ^ swz) * 8));
          acc[fd] = __builtin_amdgcn_mfma_f32_16x16x32_bf16(pa, vb, acc[fd], 0, 0, 0);
        }
      }
      __builtin_amdgcn_s_setprio(0);
      __syncthreads();
      cur ^= 1;
    }

    u16* ob = O + (size_t)(b * S + q0 + lg * 4) * H + h * HD;
    #pragma unroll
    for (int r = 0; r < 4; ++r) {
      float inv = 1.f / lrun[r];
      #pragma unroll
      for (int fd = 0; fd < 8; ++fd)
        ob[(size_t)r * H + fd * 16 + lr] = f2bf(acc[fd][r] * inv);
    }
  }
}

// ---------------- launch ----------------
extern "C" void kernel_launch(void* const* d_in, const int* in_sizes, int n_in,
                              void* d_out, int out_size, void* d_ws, size_t ws_size,
                              hipStream_t stream) {
  const float* x  = (const float*)d_in[0];
  const float* wq = (const float*)d_in[1];
  const float* bq = (const float*)d_in[2];
  const float* wk = (const float*)d_in[3];
  const float* bk = (const float*)d_in[4];
  const float* wv = (const float*)d_in[5];
  const float* bv = (const float*)d_in[6];
  const float* wo = (const float*)d_in[7];
  const float* bo = (const float*)d_in[8];

  char* ws = (char*)d_ws;
  u16*   xb    = (u16*)(ws);                      // 16 MiB  [M][H] bf16
  u16*   wqkvb = (u16*)(ws + (16ull << 20));      // 24 MiB  [6144][2048] (Wq|Wk|Wv)
  u16*   wob   = (u16*)(ws + (40ull << 20));      //  8 MiB
  u16*   Qb    = (u16*)(ws + (48ull << 20));      // 16 MiB
  u16*   Kb    = (u16*)(ws + (64ull << 20));      // 16 MiB
  u16*   Vt    = (u16*)(ws + (80ull << 20));      // 16 MiB [bh][d][s]
  u16*   Ob    = (u16*)(ws + (96ull << 20));      // 16 MiB
  float* tab   = (float*)(ws + (112ull << 20));   //  1 MiB cos/sin
  float* bqkv  = (float*)(ws + (113ull << 20));   // 24 KiB [6144]

  cast_kernel<<<M * H / 1024, 256, 0, stream>>>(x, xb, M * H);
  cast4_kernel<<<dim3(H * H / 1024, 4), 256, 0, stream>>>(
      wq, wk, wv, wo, wqkvb, wqkvb + (size_t)H * H, wqkvb + 2ull * H * H, wob);
  rope_table_k<<<(S * 64 + 255) / 256, 256, 0, stream>>>(tab);
  concat_bias_k<<<24, 256, 0, stream>>>(bq, bk, bv, bqkv);

  gemm_qkv256<<<384, 512, 0, stream>>>(xb, wqkvb, bqkv, tab, Qb, Kb, Vt);

  attn_fwd<<<512, 256, 0, stream>>>(Qb, Kb, Vt, Ob);

  gemm_o2<<<512, 256, 0, stream>>>(Ob, wob, bo, (float*)d_out);
}

// Round 10
// 285.744 us; speedup vs baseline: 1.0810x; 1.0810x over previous
//
#include <hip/hip_runtime.h>

typedef unsigned short u16;
typedef __attribute__((ext_vector_type(8))) __bf16 bf16x8;
typedef __attribute__((ext_vector_type(4))) float f32x4;
typedef __attribute__((ext_vector_type(4))) u16 u16x4;
typedef __attribute__((ext_vector_type(8))) u16 u16x8;

constexpr int S = 2048;
constexpr int H = 2048;
constexpr int NH = 16;
constexpr int HD = 128;
constexpr int M = 4096;   // B*S
constexpr float SCALE = 0.08838834764831845f;  // 1/sqrt(128)

__device__ __forceinline__ u16 f2bf(float f) {
  union { float f; unsigned u; } v; v.f = f;
  unsigned r = v.u + 0x7fffu + ((v.u >> 16) & 1u);  // RNE
  return (u16)(r >> 16);
}
__device__ __forceinline__ float bf2f(u16 u) {
  union { unsigned u; float f; } v; v.u = ((unsigned)u) << 16;
  return v.f;
}
__device__ __forceinline__ unsigned cvt_pk_bf16(float lo, float hi) {
  unsigned r;
  asm("v_cvt_pk_bf16_f32 %0, %1, %2" : "=v"(r) : "v"(lo), "v"(hi));
  return r;
}
__device__ __forceinline__ f32x4 MFMA16(bf16x8 a, bf16x8 b, f32x4 c) {
  return __builtin_amdgcn_mfma_f32_16x16x32_bf16(a, b, c, 0, 0, 0);
}

// async global->LDS, 16 bytes per lane. LDS dest must be wave-uniform base + lane*16.
__device__ __forceinline__ void gld16(const u16* g, u16* l) {
  __builtin_amdgcn_global_load_lds(
      (const __attribute__((address_space(1))) void*)g,
      (__attribute__((address_space(3))) void*)l, 16, 0, 0);
}

#define BAR  __builtin_amdgcn_s_barrier()

// ---------------- fused prep: x cast | 4 weight casts | rope table | bias concat ----------------
// one dispatch, branch on linear block id (all streaming/memory-bound).
__global__ __launch_bounds__(256) void prep_kernel(const float* __restrict__ x,
                                                   const float* __restrict__ wq,
                                                   const float* __restrict__ wk,
                                                   const float* __restrict__ wv,
                                                   const float* __restrict__ wo,
                                                   const float* __restrict__ bq,
                                                   const float* __restrict__ bk,
                                                   const float* __restrict__ bv,
                                                   u16* __restrict__ xb,
                                                   u16* __restrict__ wqkvb,
                                                   u16* __restrict__ wob,
                                                   float* __restrict__ tab,
                                                   float* __restrict__ bqkv) {
  const int NX = (M * H) / 1024;       // 8192 blocks for x
  const int NW = (H * H) / 1024;       // 4096 blocks per weight
  int bid = blockIdx.x;
  if (bid < NX + 4 * NW) {
    const float* in;
    u16* out;
    if (bid < NX) { in = x; out = xb; }
    else {
      int z = (bid - NX) / NW;
      bid = NX + ((bid - NX) % NW);    // reuse bid as local below via i calc
      int lb = (blockIdx.x - NX) % NW;
      switch (z) {
        case 0: in = wq; out = wqkvb; break;
        case 1: in = wk; out = wqkvb + (size_t)H * H; break;
        case 2: in = wv; out = wqkvb + 2ull * H * H; break;
        default: in = wo; out = wob; break;
      }
      int i = (lb * 256 + threadIdx.x) * 4;
      float4 v = *(const float4*)(in + i);
      u16x4 o;
      o[0] = f2bf(v.x); o[1] = f2bf(v.y); o[2] = f2bf(v.z); o[3] = f2bf(v.w);
      *(u16x4*)(out + i) = o;
      return;
    }
    int i = (bid * 256 + threadIdx.x) * 4;
    float4 v = *(const float4*)(in + i);
    u16x4 o;
    o[0] = f2bf(v.x); o[1] = f2bf(v.y); o[2] = f2bf(v.z); o[3] = f2bf(v.w);
    *(u16x4*)(out + i) = o;
    return;
  }
  bid -= NX + 4 * NW;
  if (bid < 512) {                     // rope table: 2048*64 entries
    int i = bid * 256 + threadIdx.x;
    int s = i >> 6, d = i & 63;
    float freq = expf(-(float)d * (9.210340371976184f / 64.f));  // 10000^(-d/64)
    float ang = (float)s * freq;
    tab[i * 2]     = cosf(ang);
    tab[i * 2 + 1] = sinf(ang);
    return;
  }
  bid -= 512;                          // bias concat: 24 blocks
  int i = bid * 256 + threadIdx.x;     // 0..6143
  const float* src = (i < 2048) ? bq : (i < 4096) ? bk : bv;
  bqkv[i] = src[i & 2047];
}

// ================= 128x128 GEMM, BK=32, 3-buffer 2-deep pipeline, counted vmcnt =================
// C[m,n] = sum_k A[m,k]*W[n,k] + bias[n]; K=2048 -> 64 K-tiles.
// Per iter u:  vmcnt(4)   (retire OWN tile-u stage ops; tile u+1 stays in flight — never drain)
//              s_barrier  (publish: ALL waves' tile-u stores visible; also fences buf (u+2)%3
//                          whose last reader was compute(u-1))
//              STAGE(u+2) (4 gld16/thread; ~2 tiles of compute to hide under)
//              compute(u) (8 ds_read_b128 + 16 MFMA per wave)
// LDS 48 KiB (3 buf x (A 8K + B 8K)) -> 3 blocks/CU; VGPR ~130 -> 12 waves/CU.
// Swizzle: LDS[row][j16] = src chunk j16 ^ ((row>>1)&3) -> 2-way banks (free), 16B-contig source.
// EMODE 0: fp32 out. EMODE 3: fused QKV epilogue (Q/K bias+RoPE, V bias+transpose).
template<int EMODE>
__device__ __forceinline__ void gemm32(const u16* __restrict__ A,
                                       const u16* __restrict__ Bw,
                                       const float* __restrict__ bias,
                                       const float* __restrict__ tab,
                                       void* __restrict__ out0, void* __restrict__ out1,
                                       void* __restrict__ out2,
                                       int brow, int bcol,
                                       u16* AsL, u16* BsL) {
  const int t = threadIdx.x;           // 0..255
  const int w = t >> 6, l = t & 63;
  const int wr = w >> 1, wc = w & 1;
  const int lr = l & 15, lg = l >> 4;  // lg = logical 16B chunk (0..3) of the K=32 row
  const int swz = (lr >> 1) & 3;       // read-side swizzle (row = ..16*i + lr)

  f32x4 acc[4][4] = {};

  // stage decomposition: 512 chunks (128 rows x 4) per matrix, 2 chunks/thread
  const int c0 = t, c1 = 256 + t;
  const int r0 = c0 >> 2, j0 = c0 & 3;
  const int r1 = c1 >> 2, j1 = c1 & 3;

  auto STAGE = [&](int BUF, int TILE) {
    u16* da = AsL + BUF * (128 * 32);
    const u16* sa = A + (size_t)brow * H + TILE * 32;
    gld16(sa + (size_t)r0 * H + ((j0 ^ ((r0 >> 1) & 3)) * 8), da + c0 * 8);
    gld16(sa + (size_t)r1 * H + ((j1 ^ ((r1 >> 1) & 3)) * 8), da + c1 * 8);
    u16* db = BsL + BUF * (128 * 32);
    const u16* sb = Bw + (size_t)bcol * H + TILE * 32;
    gld16(sb + (size_t)r0 * H + ((j0 ^ ((r0 >> 1) & 3)) * 8), db + c0 * 8);
    gld16(sb + (size_t)r1 * H + ((j1 ^ ((r1 >> 1) & 3)) * 8), db + c1 * 8);
  };
  auto LDA = [&](int BUF, bf16x8* aa) {
    const u16* base = AsL + BUF * (128 * 32) + (wr * 64 + lr) * 32;
    #pragma unroll
    for (int i = 0; i < 4; ++i)
      aa[i] = *(const bf16x8*)(base + i * (16 * 32) + ((lg ^ swz) * 8));
  };
  auto LDB = [&](int BUF, bf16x8* bb) {
    const u16* base = BsL + BUF * (128 * 32) + (wc * 64 + lr) * 32;
    #pragma unroll
    for (int n = 0; n < 4; ++n)
      bb[n] = *(const bf16x8*)(base + n * (16 * 32) + ((lg ^ swz) * 8));
  };
  auto MM = [&](bf16x8* aa, bf16x8* bb) {
    __builtin_amdgcn_s_setprio(1);
    #pragma unroll
    for (int i = 0; i < 4; ++i)
      #pragma unroll
      for (int n = 0; n < 4; ++n)
        acc[i][n] = MFMA16(aa[i], bb[n], acc[i][n]);
    __builtin_amdgcn_s_setprio(0);
  };

  // prologue: tiles 0 and 1 in flight (8 ops/thread outstanding)
  STAGE(0, 0);
  STAGE(1, 1);

  int cc = 0, cs = 2;
  for (int u = 0; u < 62; ++u) {
    asm volatile("s_waitcnt vmcnt(4)" ::: "memory");   // own tile-u ops retired
    BAR;                                               // everyone's tile-u visible
    STAGE(cs, u + 2);
    bf16x8 aa[4], bb[4];
    LDA(cc, aa); LDB(cc, bb); MM(aa, bb);
    cc = (cc == 2) ? 0 : cc + 1;
    cs = (cs == 2) ? 0 : cs + 1;
  }
  // u = 62 (tiles 62,63 in flight)
  asm volatile("s_waitcnt vmcnt(4)" ::: "memory");
  BAR;
  {
    bf16x8 aa[4], bb[4];
    LDA(cc, aa); LDB(cc, bb); MM(aa, bb);
    cc = (cc == 2) ? 0 : cc + 1;
  }
  // u = 63
  asm volatile("s_waitcnt vmcnt(0)" ::: "memory");
  BAR;
  {
    bf16x8 aa[4], bb[4];
    LDA(cc, aa); LDB(cc, bb); MM(aa, bb);
  }

  // ================= epilogue =================
  if constexpr (EMODE == 0) {
    float* C = (float*)out0;
    #pragma unroll
    for (int m = 0; m < 4; ++m) {
      const int row0 = brow + wr * 64 + m * 16 + lg * 4;
      #pragma unroll
      for (int n = 0; n < 4; ++n) {
        const int col = bcol + wc * 64 + n * 16 + lr;
        const float bv = bias[col];
        #pragma unroll
        for (int r = 0; r < 4; ++r)
          C[(size_t)(row0 + r) * H + col] = acc[m][n][r] + bv;
      }
    }
  } else {
    const int sel = bcol >> 11;          // 0=Q 1=K 2=V (128-tile never crosses)
    if (sel < 2) {
      // Q/K: bias + RoPE + bf16. Pair-exchange (d ^ 64 <-> wave w^1) via LDS.
      float* lf = (float*)AsL;           // 4 waves * 16*66 * 4B = 16.9 KiB < 24 KiB
      u16* Cq = sel ? (u16*)out1 : (u16*)out0;
      const float scl = sel ? 1.f : SCALE;
      #pragma unroll
      for (int m = 0; m < 4; ++m) {
        __syncthreads();
        float mine[4][4];
        #pragma unroll
        for (int n = 0; n < 4; ++n) {
          const float bv = bias[bcol + wc * 64 + n * 16 + lr];
          #pragma unroll
          for (int r = 0; r < 4; ++r) {
            mine[n][r] = acc[m][n][r] + bv;
            lf[w * (16 * 66) + (lg * 4 + r) * 66 + n * 16 + lr] = mine[n][r];
          }
        }
        __syncthreads();
        #pragma unroll
        for (int n = 0; n < 4; ++n) {
          const int j = n * 16 + lr;                 // d & 63
          const int hcol = (bcol & 2047) + wc * 64 + j;
          #pragma unroll
          for (int r = 0; r < 4; ++r) {
            const int row = brow + wr * 64 + m * 16 + lg * 4 + r;
            const int s = row & (S - 1);
            float pr = lf[(w ^ 1) * (16 * 66) + (lg * 4 + r) * 66 + j];
            float2 cs2 = ((const float2*)tab)[s * 64 + j];
            float out = wc ? (mine[n][r] * cs2.x + pr * cs2.y)
                           : (mine[n][r] * cs2.x - pr * cs2.y);
            Cq[(size_t)row * H + hcol] = f2bf(out * scl);
          }
        }
      }
    } else {
      // V: bias + transposed store Vt[((b*16+h)*128+d)*S + s]
      u16* Vt = (u16*)out2;
      #pragma unroll
      for (int m = 0; m < 4; ++m) {
        const int row0 = brow + wr * 64 + m * 16 + lg * 4;
        #pragma unroll
        for (int n = 0; n < 4; ++n) {
          const int col = (bcol & 2047) + wc * 64 + n * 16 + lr;
          const float bv = bias[bcol + wc * 64 + n * 16 + lr];
          const int hh = col >> 7, d = col & 127;
          const int b = row0 >> 11, s0 = row0 & (S - 1);
          u16x4 pk;
          #pragma unroll
          for (int r = 0; r < 4; ++r) pk[r] = f2bf(acc[m][n][r] + bv);
          *(u16x4*)(Vt + ((size_t)((b * 16 + hh) * 128 + d)) * S + s0) = pk;
        }
      }
    }
  }
}

// fused QKV: M=4096 x N=6144, 128x128 tiles -> 32x48 = 1536 blocks (2 rounds @3/CU).
__global__ __launch_bounds__(256, 3) void gemm_qkv32(const u16* __restrict__ xb,
                                                     const u16* __restrict__ wqkv,
                                                     const float* __restrict__ bqkv,
                                                     const float* __restrict__ tab,
                                                     u16* Qb, u16* Kb, u16* Vt) {
  __shared__ u16 AsL[3 * 128 * 32];   // 24 KiB
  __shared__ u16 BsL[3 * 128 * 32];   // 24 KiB
  const int id = blockIdx.x;
  const int xcd = id & 7, sid = id >> 3;        // sid 0..191
  const int bx = xcd * 6 + (sid % 6);           // 0..47 (per-XCD B-stripe 3 MB -> L2)
  const int by = sid / 6;                       // 0..31
  gemm32<3>(xb, wqkv, bqkv, tab, Qb, Kb, Vt, by * 128, bx * 128, AsL, BsL);
}

// out-proj: M=4096 x N=2048 -> 32x16 = 512 blocks.
__global__ __launch_bounds__(256, 3) void gemm_o32(const u16* __restrict__ A,
                                                   const u16* __restrict__ W,
                                                   const float* __restrict__ bias,
                                                   float* __restrict__ C) {
  __shared__ u16 AsL[3 * 128 * 32];   // 24 KiB
  __shared__ u16 BsL[3 * 128 * 32];   // 24 KiB
  const int id = blockIdx.x;
  const int xcd = id & 7, sid = id >> 3;        // sid 0..63
  const int bx = xcd * 2 + (sid & 1);           // 0..15
  const int by = sid >> 1;                      // 0..31
  gemm32<0>(A, W, bias, nullptr, C, nullptr, nullptr, by * 128, bx * 128, AsL, BsL);
}

// ---------------- causal flash attention (unchanged from R8) ----------------
__global__ __launch_bounds__(256) void attn_fwd(const u16* __restrict__ Q,
                                                const u16* __restrict__ Kx,
                                                const u16* __restrict__ Vt,
                                                u16* __restrict__ O) {
  const int id = blockIdx.x;
  const int xcd = id & 7, slot = id >> 3;
  const int bh = (slot >> 4) * 8 + xcd;    // 0..31
  const int pid = slot & 15;               // 0..15
  const int b = bh >> 4, h = bh & 15;
  const int t = threadIdx.x, w = t >> 6, l = t & 63;
  const int lr = l & 15, lg = l >> 4;
  const int swz = lr & 7;

  __shared__ u16 Ks[2][64 * 128];
  __shared__ u16 Vs[2][128 * 64];
  __shared__ u16 P_lds[4][16 * 64];
  u16* pw = &P_lds[w][0];

  const u16* kbase = Kx + (size_t)(b * S) * H + h * HD;
  const u16* vbase = Vt + (size_t)bh * HD * S;

  auto stageK = [&](int bf, int k0) {
    #pragma unroll
    for (int it = 0; it < 4; ++it) {
      int c = it * 256 + t;
      int row = c >> 4, j = c & 15;
      gld16(kbase + (size_t)(k0 + row) * H + ((j ^ (row & 7)) * 8), &Ks[bf][0] + c * 8);
    }
  };
  auto stageV = [&](int bf, int k0) {
    #pragma unroll
    for (int it = 0; it < 4; ++it) {
      int c = it * 256 + t;
      int row = c >> 3, j = c & 7;
      gld16(vbase + (size_t)row * S + k0 + ((j ^ (row & 7)) * 8), &Vs[bf][0] + c * 8);
    }
  };

  int cur = 0;
  for (int qi = 0; qi < 2; ++qi) {
    const int qt = qi ? pid : (31 - pid);
    const int q0 = qt * 64 + w * 16;

    bf16x8 qa[4];
    const u16* qbase = Q + (size_t)(b * S + q0 + lr) * H + h * HD;
    #pragma unroll
    for (int ks = 0; ks < 4; ++ks)
      qa[ks] = *(const bf16x8*)(qbase + ks * 32 + lg * 8);

    f32x4 acc[8] = {};
    float mrun[4], lrun[4];
    #pragma unroll
    for (int r = 0; r < 4; ++r) { mrun[r] = -1e30f; lrun[r] = 0.f; }

    __syncthreads();
    stageK(cur, 0);
    stageV(cur, 0);
    __syncthreads();

    for (int kt = 0; kt <= qt; ++kt) {
      if (kt < qt) {
        stageK(cur ^ 1, (kt + 1) * 64);
        stageV(cur ^ 1, (kt + 1) * 64);
      }
      const u16* kl = &Ks[cur][0];
      const u16* vl = &Vs[cur][0];

      f32x4 sc[4] = {};
      __builtin_amdgcn_s_setprio(1);
      #pragma unroll
      for (int ks = 0; ks < 4; ++ks) {
        #pragma unroll
        for (int f = 0; f < 4; ++f) {
          bf16x8 kf = *(const bf16x8*)(kl + (f * 16 + lr) * 128 + (((ks * 4 + lg) ^ swz) * 8));
          sc[f] = __builtin_amdgcn_mfma_f32_16x16x32_bf16(qa[ks], kf, sc[f], 0, 0, 0);
        }
      }
      __builtin_amdgcn_s_setprio(0);
      const bool diag = (kt == qt);
      float p[4][4];
      #pragma unroll
      for (int f = 0; f < 4; ++f)
        #pragma unroll
        for (int r = 0; r < 4; ++r) {
          float v = sc[f][r];
          if (diag && (f * 16 + lr > w * 16 + lg * 4 + r)) v = -1e30f;
          p[f][r] = v;
        }
      float mx[4];
      #pragma unroll
      for (int r = 0; r < 4; ++r) {
        float m0 = fmaxf(fmaxf(p[0][r], p[1][r]), fmaxf(p[2][r], p[3][r]));
        m0 = fmaxf(m0, __shfl_xor(m0, 1));
        m0 = fmaxf(m0, __shfl_xor(m0, 2));
        m0 = fmaxf(m0, __shfl_xor(m0, 4));
        m0 = fmaxf(m0, __shfl_xor(m0, 8));
        mx[r] = m0;
      }
      bool grow = (mx[0] > mrun[0] + 8.f) || (mx[1] > mrun[1] + 8.f) ||
                  (mx[2] > mrun[2] + 8.f) || (mx[3] > mrun[3] + 8.f);
      if (__any(grow)) {
        float resc[4];
        #pragma unroll
        for (int r = 0; r < 4; ++r) {
          float mnew = fmaxf(mrun[r], mx[r]);
          resc[r] = __expf(mrun[r] - mnew);
          mrun[r] = mnew;
          lrun[r] *= resc[r];
        }
        #pragma unroll
        for (int fd = 0; fd < 8; ++fd) {
          f32x4 a = acc[fd];
          a[0] *= resc[0]; a[1] *= resc[1]; a[2] *= resc[2]; a[3] *= resc[3];
          acc[fd] = a;
        }
      }
      #pragma unroll
      for (int r = 0; r < 4; ++r) {
        float sum = 0.f;
        #pragma unroll
        for (int f = 0; f < 4; ++f) {
          float e = __expf(p[f][r] - mrun[r]);
          p[f][r] = e;
          sum += e;
        }
        sum += __shfl_xor(sum, 1);
        sum += __shfl_xor(sum, 2);
        sum += __shfl_xor(sum, 4);
        sum += __shfl_xor(sum, 8);
        lrun[r] += sum;
      }
      {
        const int r0 = lg * 4;
        #pragma unroll
        for (int f = 0; f < 4; ++f) {
          const int col = f * 16 + lr;
          unsigned w01 = cvt_pk_bf16(p[f][0], p[f][1]);
          unsigned w23 = cvt_pk_bf16(p[f][2], p[f][3]);
          pw[(r0 + 0) * 64 + (col ^ (((r0 + 0) & 7) << 3))] = (u16)(w01 & 0xffffu);
          pw[(r0 + 1) * 64 + (col ^ (((r0 + 1) & 7) << 3))] = (u16)(w01 >> 16);
          pw[(r0 + 2) * 64 + (col ^ (((r0 + 2) & 7) << 3))] = (u16)(w23 & 0xffffu);
          pw[(r0 + 3) * 64 + (col ^ (((r0 + 3) & 7) << 3))] = (u16)(w23 >> 16);
        }
      }
      __builtin_amdgcn_s_setprio(1);
      #pragma unroll
      for (int ks = 0; ks < 2; ++ks) {
        int col0 = ks * 32 + lg * 8;
        bf16x8 pa = *(const bf16x8*)(pw + lr * 64 + (col0 ^ (swz << 3)));
        #pragma unroll
        for (int fd = 0; fd < 8; ++fd) {
          bf16x8 vb = *(const bf16x8*)(vl + (fd * 16 + lr) * 64 + (((ks * 4 + lg) ^ swz) * 8));
          acc[fd] = __builtin_amdgcn_mfma_f32_16x16x32_bf16(pa, vb, acc[fd], 0, 0, 0);
        }
      }
      __builtin_amdgcn_s_setprio(0);
      __syncthreads();
      cur ^= 1;
    }

    u16* ob = O + (size_t)(b * S + q0 + lg * 4) * H + h * HD;
    #pragma unroll
    for (int r = 0; r < 4; ++r) {
      float inv = 1.f / lrun[r];
      #pragma unroll
      for (int fd = 0; fd < 8; ++fd)
        ob[(size_t)r * H + fd * 16 + lr] = f2bf(acc[fd][r] * inv);
    }
  }
}

// ---------------- launch ----------------
extern "C" void kernel_launch(void* const* d_in, const int* in_sizes, int n_in,
                              void* d_out, int out_size, void* d_ws, size_t ws_size,
                              hipStream_t stream) {
  const float* x  = (const float*)d_in[0];
  const float* wq = (const float*)d_in[1];
  const float* bq = (const float*)d_in[2];
  const float* wk = (const float*)d_in[3];
  const float* bk = (const float*)d_in[4];
  const float* wv = (const float*)d_in[5];
  const float* bv = (const float*)d_in[6];
  const float* wo = (const float*)d_in[7];
  const float* bo = (const float*)d_in[8];

  char* ws = (char*)d_ws;
  u16*   xb    = (u16*)(ws);                      // 16 MiB  [M][H] bf16
  u16*   wqkvb = (u16*)(ws + (16ull << 20));      // 24 MiB  [6144][2048] (Wq|Wk|Wv)
  u16*   wob   = (u16*)(ws + (40ull << 20));      //  8 MiB
  u16*   Qb    = (u16*)(ws + (48ull << 20));      // 16 MiB
  u16*   Kb    = (u16*)(ws + (64ull << 20));      // 16 MiB
  u16*   Vt    = (u16*)(ws + (80ull << 20));      // 16 MiB [bh][d][s]
  u16*   Ob    = (u16*)(ws + (96ull << 20));      // 16 MiB
  float* tab   = (float*)(ws + (112ull << 20));   //  1 MiB cos/sin
  float* bqkv  = (float*)(ws + (113ull << 20));   // 24 KiB [6144]

  const int NPREP = (M * H) / 1024 + 4 * (H * H) / 1024 + 512 + 24;
  prep_kernel<<<NPREP, 256, 0, stream>>>(x, wq, wk, wv, wo, bq, bk, bv,
                                         xb, wqkvb, wob, tab, bqkv);

  gemm_qkv32<<<1536, 256, 0, stream>>>(xb, wqkvb, bqkv, tab, Qb, Kb, Vt);

  attn_fwd<<<512, 256, 0, stream>>>(Qb, Kb, Vt, Ob);

  gemm_o32<<<512, 256, 0, stream>>>(Ob, wob, bo, (float*)d_out);
}

// Round 11
// 263.588 us; speedup vs baseline: 1.1718x; 1.0841x over previous
//
#include <hip/hip_runtime.h>

typedef unsigned short u16;
typedef __attribute__((ext_vector_type(8))) __bf16 bf16x8;
typedef __attribute__((ext_vector_type(4))) float f32x4;
typedef __attribute__((ext_vector_type(4))) u16 u16x4;
typedef __attribute__((ext_vector_type(8))) u16 u16x8;

constexpr int S = 2048;
constexpr int H = 2048;
constexpr int NH = 16;
constexpr int HD = 128;
constexpr int M = 4096;   // B*S
constexpr float SCALE = 0.08838834764831845f;  // 1/sqrt(128)

__device__ __forceinline__ u16 f2bf(float f) {
  union { float f; unsigned u; } v; v.f = f;
  unsigned r = v.u + 0x7fffu + ((v.u >> 16) & 1u);  // RNE
  return (u16)(r >> 16);
}
__device__ __forceinline__ float bf2f(u16 u) {
  union { unsigned u; float f; } v; v.u = ((unsigned)u) << 16;
  return v.f;
}
__device__ __forceinline__ unsigned cvt_pk_bf16(float lo, float hi) {
  unsigned r;
  asm("v_cvt_pk_bf16_f32 %0, %1, %2" : "=v"(r) : "v"(lo), "v"(hi));
  return r;
}
__device__ __forceinline__ f32x4 MFMA16(bf16x8 a, bf16x8 b, f32x4 c) {
  return __builtin_amdgcn_mfma_f32_16x16x32_bf16(a, b, c, 0, 0, 0);
}

// async global->LDS, 16 bytes per lane. LDS dest must be wave-uniform base + lane*16.
__device__ __forceinline__ void gld16(const u16* g, u16* l) {
  __builtin_amdgcn_global_load_lds(
      (const __attribute__((address_space(1))) void*)g,
      (__attribute__((address_space(3))) void*)l, 16, 0, 0);
}

#define SBAR  { __builtin_amdgcn_sched_barrier(0); __builtin_amdgcn_s_barrier(); __builtin_amdgcn_sched_barrier(0); }
#define LGKM0 { asm volatile("s_waitcnt lgkmcnt(0)" ::: "memory"); __builtin_amdgcn_sched_barrier(0); }

// ---------------- fused prep: x cast | 4 weight casts (Q/K pair-interleaved) | rope table | bias ----------------
// Q/K weight-row permutation: head-dim d<64 -> 2d, d>=64 -> 2(d-64)+1. RoPE partners (d,d+64)
// become adjacent output columns -> GEMM-epilogue RoPE needs only __shfl_xor(x,1).
// Q,K share the permutation => QK^T invariant. V and Wo untouched.
__global__ __launch_bounds__(256) void prep_kernel(const float* __restrict__ x,
                                                   const float* __restrict__ wq,
                                                   const float* __restrict__ wk,
                                                   const float* __restrict__ wv,
                                                   const float* __restrict__ wo,
                                                   const float* __restrict__ bq,
                                                   const float* __restrict__ bk,
                                                   const float* __restrict__ bv,
                                                   u16* __restrict__ xb,
                                                   u16* __restrict__ wqkvb,
                                                   u16* __restrict__ wob,
                                                   float* __restrict__ tab,
                                                   float* __restrict__ bqkv) {
  const int NX = (M * H) / 1024;       // 8192 blocks for x
  const int NW = (H * H) / 1024;       // 4096 blocks per weight
  int bid = blockIdx.x;
  if (bid < NX) {                      // x cast, straight
    int i = (bid * 256 + threadIdx.x) * 4;
    float4 v = *(const float4*)(x + i);
    u16x4 o;
    o[0] = f2bf(v.x); o[1] = f2bf(v.y); o[2] = f2bf(v.z); o[3] = f2bf(v.w);
    *(u16x4*)(xb + i) = o;
    return;
  }
  bid -= NX;
  if (bid < 4 * NW) {                  // weight casts
    const int z = bid / NW, lb = bid % NW;
    const float* in;
    u16* out;
    switch (z) {
      case 0: in = wq; out = wqkvb; break;
      case 1: in = wk; out = wqkvb + (size_t)H * H; break;
      case 2: in = wv; out = wqkvb + 2ull * H * H; break;
      default: in = wo; out = wob; break;
    }
    int i = (lb * 256 + threadIdx.x) * 4;        // OUTPUT flat index
    int ro = i >> 11, cb = i & 2047;
    int rin = ro;
    if (z < 2) {                                  // gather from permuted source row
      int nd = ro & 127;
      int od = (nd & 1) ? (nd >> 1) + 64 : (nd >> 1);
      rin = (ro & ~127) | od;
    }
    float4 v = *(const float4*)(in + (size_t)rin * H + cb);
    u16x4 o;
    o[0] = f2bf(v.x); o[1] = f2bf(v.y); o[2] = f2bf(v.z); o[3] = f2bf(v.w);
    *(u16x4*)(out + i) = o;
    return;
  }
  bid -= 4 * NW;
  if (bid < 512) {                     // rope table: [2048][64] x (cos,sin)
    int i = bid * 256 + threadIdx.x;
    int s = i >> 6, d = i & 63;
    float freq = expf(-(float)d * (9.210340371976184f / 64.f));  // 10000^(-d/64)
    float ang = (float)s * freq;
    tab[i * 2]     = cosf(ang);
    tab[i * 2 + 1] = sinf(ang);
    return;
  }
  bid -= 512;                          // bias concat (Q/K permuted): 24 blocks
  int i = bid * 256 + threadIdx.x;     // 0..6143
  if (i < 4096) {
    const float* src = (i < 2048) ? bq : bk;
    int base = i & 2047;
    int nd = base & 127;
    int od = (nd & 1) ? (nd >> 1) + 64 : (nd >> 1);
    bqkv[i] = src[(base & ~127) | od];
  } else {
    bqkv[i] = bv[i & 2047];
  }
}

// ================= R5-proven 256(M) x NW*64(N) 8-phase GEMM =================
// C[m,n] = sum_k A[m,k]*W[n,k] + bias[n]; K=2048, BK=64 (32 K-tiles, 16 iters x 2).
// 8 waves (2M x 4N), per-wave 128 x NW*16. LDS: A 2x[256][64], B 2x[NW*64][64].
// Chunk-XOR swizzle (source-swizzled stage, same involution on ds_read) -> 0 conflicts.
// Stage ledger: ph1 A1h0, ph2 A1h1, ph4 B0<-u+2 + GATE; ph5/6 A0 halves, ph8 B1<-u+3 + GATE.
// EMODE 0: fp32 out. EMODE 3: fused QKV (Q/K: bias + shfl-pair RoPE; V: bias + transpose).
template<int NW, int EMODE>
__device__ __forceinline__ void gemm_body(const u16* __restrict__ A,
                                          const u16* __restrict__ Bw,
                                          const float* __restrict__ bias,
                                          const float* __restrict__ tab,
                                          void* __restrict__ out0, void* __restrict__ out1,
                                          void* __restrict__ out2,
                                          int brow, int bcol,
                                          u16* AsL, u16* BsL) {
  const int t = threadIdx.x;
  const int w = t >> 6, l = t & 63;
  const int wr = w >> 2, wc = w & 3;
  const int lr = l & 15, lg = l >> 4;
  const int swz = lr & 7;

  f32x4 acc[8][NW] = {};
  bf16x8 af[4], b0[NW], b1[NW];

  const int sr = t >> 3, sj = t & 7;   // stage row (0..63) / chunk (0..7)

  auto STAGE_A = [&](int BUF, int HALF, int TILE) {
    u16* d = AsL + BUF * (256 * 64) + HALF * (128 * 64);
    const u16* sp = A + (size_t)(brow + HALF * 128) * H + TILE * 64;
    gld16(sp + (size_t)sr * H        + ((sj ^ (sr & 7)) * 8), d + t * 8);
    gld16(sp + (size_t)(64 + sr) * H + ((sj ^ (sr & 7)) * 8), d + (512 + t) * 8);
  };
  auto STAGE_B = [&](int BUF, int TILE) {
    u16* d = BsL + BUF * (NW * 64 * 64);
    const u16* sp = Bw + (size_t)bcol * H + TILE * 64;
    #pragma unroll
    for (int i = 0; i < NW; ++i)
      gld16(sp + (size_t)(i * 64 + sr) * H + ((sj ^ (sr & 7)) * 8),
            d + (i * 512 + t) * 8);
  };
  auto LDA = [&](int BUF, int KH, int MB) {
    const u16* base = AsL + BUF * (256 * 64) + (wr * 128 + MB * 16 + lr) * 64;
    #pragma unroll
    for (int i = 0; i < 4; ++i)
      af[i] = *(const bf16x8*)(base + i * (16 * 64) + (((KH * 4 + lg) ^ swz) * 8));
  };
  auto LDB = [&](int BUF, int KH, bf16x8* bb) {
    const u16* base = BsL + BUF * (NW * 64 * 64) + (wc * (NW * 16) + lr) * 64;
    #pragma unroll
    for (int n = 0; n < NW; ++n)
      bb[n] = *(const bf16x8*)(base + n * (16 * 64) + (((KH * 4 + lg) ^ swz) * 8));
  };
  auto MM = [&](int MB, bf16x8* bb) {
    __builtin_amdgcn_s_setprio(1);
    #pragma unroll
    for (int i = 0; i < 4; ++i)
      #pragma unroll
      for (int n = 0; n < NW; ++n)
        acc[MB + i][n] = MFMA16(af[i], bb[n], acc[MB + i][n]);
    __builtin_amdgcn_s_setprio(0);
  };
  auto GATE = [&]() {
    if constexpr (NW == 3) { asm volatile("s_waitcnt vmcnt(3)" ::: "memory"); }
    else                   { asm volatile("s_waitcnt vmcnt(2)" ::: "memory"); }
  };

  // prologue: A0<-t0, B0<-t0, B1<-t1; retire all but B1
  STAGE_A(0, 0, 0); STAGE_A(0, 1, 0);
  STAGE_B(0, 0);
  STAGE_B(1, 1);
  GATE();
  SBAR;

  for (int J = 0; J < 16; ++J) {
    const int u = 2 * J;
    const bool more = (J < 15);
    // ---- tile u (buf0) ----
    LDA(0, 0, 0); LDB(0, 0, b0);
    STAGE_A(1, 0, u + 1);
    SBAR; LGKM0; MM(0, b0); SBAR;
    LDA(0, 0, 4);
    STAGE_A(1, 1, u + 1);
    SBAR; LGKM0; MM(4, b0); SBAR;
    LDA(0, 1, 0); LDB(0, 1, b1);
    SBAR; LGKM0; MM(0, b1); SBAR;
    LDA(0, 1, 4);
    if (more) STAGE_B(0, u + 2);
    SBAR; LGKM0; MM(4, b1);
    if (more) { GATE(); } else { asm volatile("s_waitcnt vmcnt(0)" ::: "memory"); }
    SBAR;
    // ---- tile u+1 (buf1) ----
    LDA(1, 0, 0); LDB(1, 0, b0);
    if (more) STAGE_A(0, 0, u + 2);
    SBAR; LGKM0; MM(0, b0); SBAR;
    LDA(1, 0, 4);
    if (more) STAGE_A(0, 1, u + 2);
    SBAR; LGKM0; MM(4, b0); SBAR;
    LDA(1, 1, 0); LDB(1, 1, b1);
    SBAR; LGKM0; MM(0, b1); SBAR;
    LDA(1, 1, 4);
    if (more) STAGE_B(1, u + 3);
    SBAR; LGKM0; MM(4, b1);
    if (more) { GATE(); SBAR; }
  }

  // ---- epilogue ----
  #pragma unroll
  for (int m = 0; m < 8; ++m) {
    const int row0 = brow + wr * 128 + m * 16 + lg * 4;
    #pragma unroll
    for (int n = 0; n < NW; ++n) {
      const int gcol0 = bcol + wc * (NW * 16) + n * 16;
      const float bv2 = bias[gcol0 + lr];
      if constexpr (EMODE == 0) {
        float* C = (float*)out0;
        #pragma unroll
        for (int r = 0; r < 4; ++r)
          C[(size_t)(row0 + r) * H + gcol0 + lr] = acc[m][n][r] + bv2;
      } else {
        const int sel = gcol0 >> 11;           // wave-uniform (16-col frag never crosses 2048)
        const int col = (gcol0 & 2047) + lr;
        if (sel < 2) {
          // Q/K: bias + RoPE via shfl pair-exchange (pair-interleaved layout), + bf16
          u16* Cq = sel ? (u16*)out1 : (u16*)out0;
          const float scl = sel ? 1.f : SCALE;
          const int d = (col & 127) >> 1;      // table index (repeats at d+64)
          #pragma unroll
          for (int r = 0; r < 4; ++r) {
            const int row = row0 + r;
            const int s = row & (S - 1);
            float xv = acc[m][n][r] + bv2;
            float pr = __shfl_xor(xv, 1);      // partner: other half of the RoPE pair
            float2 cs = ((const float2*)tab)[s * 64 + d];
            float o = (lr & 1) ? (xv * cs.x + pr * cs.y)
                               : (xv * cs.x - pr * cs.y);
            Cq[(size_t)row * H + col] = f2bf(o * scl);
          }
        } else {
          // V: bias + transposed store Vt[((b*16+h)*128+d)*S + s]
          const int hh = col >> 7, d = col & 127;
          const int b = row0 >> 11, s0 = row0 & (S - 1);
          u16x4 pk;
          #pragma unroll
          for (int r = 0; r < 4; ++r) pk[r] = f2bf(acc[m][n][r] + bv2);
          *(u16x4*)((u16*)out2 + ((size_t)((b * 16 + hh) * 128 + d)) * S + s0) = pk;
        }
      }
    }
  }
}

// fused QKV: M=4096 x N=6144, 256x192 tiles -> 16x32 = 512 blocks (2 exact rounds).
__global__ __launch_bounds__(512, 2) void gemm_qkv8(const u16* __restrict__ xb,
                                                    const u16* __restrict__ wqkv,
                                                    const float* __restrict__ bqkv,
                                                    const float* __restrict__ tab,
                                                    u16* Qb, u16* Kb, u16* Vt) {
  __shared__ u16 AsL[2 * 256 * 64];   // 64 KiB
  __shared__ u16 BsL[2 * 192 * 64];   // 48 KiB
  const int id = blockIdx.x;
  const int xcd = id & 7, sid = id >> 3;
  const int bx = xcd * 4 + (sid & 3), by = sid >> 2;
  gemm_body<3, 3>(xb, wqkv, bqkv, tab, Qb, Kb, Vt, by * 256, bx * 192, AsL, BsL);
}

// out-proj: M=4096 x N=2048, 256x128 tiles -> 16x16 = 256 blocks (1 exact round).
__global__ __launch_bounds__(512, 2) void gemm_o8(const u16* __restrict__ A,
                                                  const u16* __restrict__ W,
                                                  const float* __restrict__ bias,
                                                  float* __restrict__ C) {
  __shared__ u16 AsL[2 * 256 * 64];   // 64 KiB
  __shared__ u16 BsL[2 * 128 * 64];   // 32 KiB
  const int id = blockIdx.x;
  const int xcd = id & 7, sid = id >> 3;
  const int bx = xcd * 2 + (sid & 1), by = sid >> 1;
  gemm_body<2, 0>(A, W, bias, nullptr, C, nullptr, nullptr, by * 256, bx * 128, AsL, BsL);
}

// ---------------- causal flash attention (unchanged; Q/K permutation is transparent) ----------------
__global__ __launch_bounds__(256) void attn_fwd(const u16* __restrict__ Q,
                                                const u16* __restrict__ Kx,
                                                const u16* __restrict__ Vt,
                                                u16* __restrict__ O) {
  const int id = blockIdx.x;
  const int xcd = id & 7, slot = id >> 3;
  const int bh = (slot >> 4) * 8 + xcd;    // 0..31
  const int pid = slot & 15;               // 0..15
  const int b = bh >> 4, h = bh & 15;
  const int t = threadIdx.x, w = t >> 6, l = t & 63;
  const int lr = l & 15, lg = l >> 4;
  const int swz = lr & 7;

  __shared__ u16 Ks[2][64 * 128];
  __shared__ u16 Vs[2][128 * 64];
  __shared__ u16 P_lds[4][16 * 64];
  u16* pw = &P_lds[w][0];

  const u16* kbase = Kx + (size_t)(b * S) * H + h * HD;
  const u16* vbase = Vt + (size_t)bh * HD * S;

  auto stageK = [&](int bf, int k0) {
    #pragma unroll
    for (int it = 0; it < 4; ++it) {
      int c = it * 256 + t;
      int row = c >> 4, j = c & 15;
      gld16(kbase + (size_t)(k0 + row) * H + ((j ^ (row & 7)) * 8), &Ks[bf][0] + c * 8);
    }
  };
  auto stageV = [&](int bf, int k0) {
    #pragma unroll
    for (int it = 0; it < 4; ++it) {
      int c = it * 256 + t;
      int row = c >> 3, j = c & 7;
      gld16(vbase + (size_t)row * S + k0 + ((j ^ (row & 7)) * 8), &Vs[bf][0] + c * 8);
    }
  };

  int cur = 0;
  for (int qi = 0; qi < 2; ++qi) {
    const int qt = qi ? pid : (31 - pid);
    const int q0 = qt * 64 + w * 16;

    bf16x8 qa[4];
    const u16* qbase = Q + (size_t)(b * S + q0 + lr) * H + h * HD;
    #pragma unroll
    for (int ks = 0; ks < 4; ++ks)
      qa[ks] = *(const bf16x8*)(qbase + ks * 32 + lg * 8);

    f32x4 acc[8] = {};
    float mrun[4], lrun[4];
    #pragma unroll
    for (int r = 0; r < 4; ++r) { mrun[r] = -1e30f; lrun[r] = 0.f; }

    __syncthreads();
    stageK(cur, 0);
    stageV(cur, 0);
    __syncthreads();

    for (int kt = 0; kt <= qt; ++kt) {
      if (kt < qt) {
        stageK(cur ^ 1, (kt + 1) * 64);
        stageV(cur ^ 1, (kt + 1) * 64);
      }
      const u16* kl = &Ks[cur][0];
      const u16* vl = &Vs[cur][0];

      f32x4 sc[4] = {};
      __builtin_amdgcn_s_setprio(1);
      #pragma unroll
      for (int ks = 0; ks < 4; ++ks) {
        #pragma unroll
        for (int f = 0; f < 4; ++f) {
          bf16x8 kf = *(const bf16x8*)(kl + (f * 16 + lr) * 128 + (((ks * 4 + lg) ^ swz) * 8));
          sc[f] = __builtin_amdgcn_mfma_f32_16x16x32_bf16(qa[ks], kf, sc[f], 0, 0, 0);
        }
      }
      __builtin_amdgcn_s_setprio(0);
      const bool diag = (kt == qt);
      float p[4][4];
      #pragma unroll
      for (int f = 0; f < 4; ++f)
        #pragma unroll
        for (int r = 0; r < 4; ++r) {
          float v = sc[f][r];
          if (diag && (f * 16 + lr > w * 16 + lg * 4 + r)) v = -1e30f;
          p[f][r] = v;
        }
      float mx[4];
      #pragma unroll
      for (int r = 0; r < 4; ++r) {
        float m0 = fmaxf(fmaxf(p[0][r], p[1][r]), fmaxf(p[2][r], p[3][r]));
        m0 = fmaxf(m0, __shfl_xor(m0, 1));
        m0 = fmaxf(m0, __shfl_xor(m0, 2));
        m0 = fmaxf(m0, __shfl_xor(m0, 4));
        m0 = fmaxf(m0, __shfl_xor(m0, 8));
        mx[r] = m0;
      }
      bool grow = (mx[0] > mrun[0] + 8.f) || (mx[1] > mrun[1] + 8.f) ||
                  (mx[2] > mrun[2] + 8.f) || (mx[3] > mrun[3] + 8.f);
      if (__any(grow)) {
        float resc[4];
        #pragma unroll
        for (int r = 0; r < 4; ++r) {
          float mnew = fmaxf(mrun[r], mx[r]);
          resc[r] = __expf(mrun[r] - mnew);
          mrun[r] = mnew;
          lrun[r] *= resc[r];
        }
        #pragma unroll
        for (int fd = 0; fd < 8; ++fd) {
          f32x4 a = acc[fd];
          a[0] *= resc[0]; a[1] *= resc[1]; a[2] *= resc[2]; a[3] *= resc[3];
          acc[fd] = a;
        }
      }
      #pragma unroll
      for (int r = 0; r < 4; ++r) {
        float sum = 0.f;
        #pragma unroll
        for (int f = 0; f < 4; ++f) {
          float e = __expf(p[f][r] - mrun[r]);
          p[f][r] = e;
          sum += e;
        }
        sum += __shfl_xor(sum, 1);
        sum += __shfl_xor(sum, 2);
        sum += __shfl_xor(sum, 4);
        sum += __shfl_xor(sum, 8);
        lrun[r] += sum;
      }
      {
        const int r0 = lg * 4;
        #pragma unroll
        for (int f = 0; f < 4; ++f) {
          const int col = f * 16 + lr;
          unsigned w01 = cvt_pk_bf16(p[f][0], p[f][1]);
          unsigned w23 = cvt_pk_bf16(p[f][2], p[f][3]);
          pw[(r0 + 0) * 64 + (col ^ (((r0 + 0) & 7) << 3))] = (u16)(w01 & 0xffffu);
          pw[(r0 + 1) * 64 + (col ^ (((r0 + 1) & 7) << 3))] = (u16)(w01 >> 16);
          pw[(r0 + 2) * 64 + (col ^ (((r0 + 2) & 7) << 3))] = (u16)(w23 & 0xffffu);
          pw[(r0 + 3) * 64 + (col ^ (((r0 + 3) & 7) << 3))] = (u16)(w23 >> 16);
        }
      }
      __builtin_amdgcn_s_setprio(1);
      #pragma unroll
      for (int ks = 0; ks < 2; ++ks) {
        int col0 = ks * 32 + lg * 8;
        bf16x8 pa = *(const bf16x8*)(pw + lr * 64 + (col0 ^ (swz << 3)));
        #pragma unroll
        for (int fd = 0; fd < 8; ++fd) {
          bf16x8 vb = *(const bf16x8*)(vl + (fd * 16 + lr) * 64 + (((ks * 4 + lg) ^ swz) * 8));
          acc[fd] = __builtin_amdgcn_mfma_f32_16x16x32_bf16(pa, vb, acc[fd], 0, 0, 0);
        }
      }
      __builtin_amdgcn_s_setprio(0);
      __syncthreads();
      cur ^= 1;
    }

    u16* ob = O + (size_t)(b * S + q0 + lg * 4) * H + h * HD;
    #pragma unroll
    for (int r = 0; r < 4; ++r) {
      float inv = 1.f / lrun[r];
      #pragma unroll
      for (int fd = 0; fd < 8; ++fd)
        ob[(size_t)r * H + fd * 16 + lr] = f2bf(acc[fd][r] * inv);
    }
  }
}

// ---------------- launch ----------------
extern "C" void kernel_launch(void* const* d_in, const int* in_sizes, int n_in,
                              void* d_out, int out_size, void* d_ws, size_t ws_size,
                              hipStream_t stream) {
  const float* x  = (const float*)d_in[0];
  const float* wq = (const float*)d_in[1];
  const float* bq = (const float*)d_in[2];
  const float* wk = (const float*)d_in[3];
  const float* bk = (const float*)d_in[4];
  const float* wv = (const float*)d_in[5];
  const float* bv = (const float*)d_in[6];
  const float* wo = (const float*)d_in[7];
  const float* bo = (const float*)d_in[8];

  char* ws = (char*)d_ws;
  u16*   xb    = (u16*)(ws);                      // 16 MiB  [M][H] bf16
  u16*   wqkvb = (u16*)(ws + (16ull << 20));      // 24 MiB  [6144][2048] (Wq|Wk|Wv, Q/K rows permuted)
  u16*   wob   = (u16*)(ws + (40ull << 20));      //  8 MiB
  u16*   Qb    = (u16*)(ws + (48ull << 20));      // 16 MiB (pair-interleaved layout)
  u16*   Kb    = (u16*)(ws + (64ull << 20));      // 16 MiB (pair-interleaved layout)
  u16*   Vt    = (u16*)(ws + (80ull << 20));      // 16 MiB [bh][d][s]
  u16*   Ob    = (u16*)(ws + (96ull << 20));      // 16 MiB
  float* tab   = (float*)(ws + (112ull << 20));   //  1 MiB cos/sin [2048][64]
  float* bqkv  = (float*)(ws + (113ull << 20));   // 24 KiB [6144] (Q/K permuted)

  const int NPREP = (M * H) / 1024 + 4 * (H * H) / 1024 + 512 + 24;
  prep_kernel<<<NPREP, 256, 0, stream>>>(x, wq, wk, wv, wo, bq, bk, bv,
                                         xb, wqkvb, wob, tab, bqkv);

  gemm_qkv8<<<512, 512, 0, stream>>>(xb, wqkvb, bqkv, tab, Qb, Kb, Vt);

  attn_fwd<<<512, 256, 0, stream>>>(Qb, Kb, Vt, Ob);

  gemm_o8<<<256, 512, 0, stream>>>(Ob, wob, bo, (float*)d_out);
}